// Round 1
// baseline (18.188 us; speedup 1.0000x reference)
//
#include <hip/hip_runtime.h>
#include <cstdint>

// Problem: out[b,f,cout,r] = logsumexp_cin( ll[b,f,cin,r] + log_softmax_cin(logits)[f,cin,cout,r] )
// Identity: = log( sum_cin exp(ll) * softmax(logits) )
// B=256, F=64, CIN=32, COUT=16, R=8
#define B_    256
#define F_    64
#define CIN_  32
#define COUT_ 16
#define R_    8

#define LOG2E 1.4426950408889634f
#define LN2   0.6931471805599453f

typedef float f32x16 __attribute__((ext_vector_type(16)));

// ---------------------------------------------------------------------------
// Prep: wt[f][cr][cin] = softmax_cin(logits[f, cin, cout, r]),  cr = cout*8 + r
// logits flat (per f): cin*128 + cr.  Output flat (per f): cr*32 + cin.
// One WG per f. 64 WGs x 256 threads.
// ---------------------------------------------------------------------------
__global__ __launch_bounds__(256) void prep_softmax(const float* __restrict__ logits,
                                                    float* __restrict__ wt) {
    __shared__ float Lg[4096];
    __shared__ float T[128 * 36];   // transposed, padded stride 36
    const int t = threadIdx.x;
    const int f = blockIdx.x;

    const float* src = logits + ((size_t)f << 12);
    #pragma unroll
    for (int it = 0; it < 4; ++it) {
        const int q = it * 256 + t;                 // float4 index 0..1023
        *(float4*)&Lg[q * 4] = *(const float4*)&src[q * 4];
    }
    __syncthreads();

    if (t < 128) {
        const int cr = t;
        float x[32];
        #pragma unroll
        for (int c = 0; c < 32; ++c) x[c] = Lg[c * 128 + cr];
        float m = x[0];
        #pragma unroll
        for (int c = 1; c < 32; ++c) m = fmaxf(m, x[c]);
        float s = 0.f;
        #pragma unroll
        for (int c = 0; c < 32; ++c) { x[c] = exp2f((x[c] - m) * LOG2E); s += x[c]; }
        const float inv = 1.0f / s;
        #pragma unroll
        for (int c = 0; c < 32; ++c) T[cr * 36 + c] = x[c] * inv;
    }
    __syncthreads();

    float* dst = wt + ((size_t)f << 12);
    #pragma unroll
    for (int it = 0; it < 4; ++it) {
        const int q  = it * 256 + t;                // float4 index 0..1023
        const int cr = q >> 3, c0 = (q & 7) << 2;
        *(float4*)&dst[q * 4] = *(const float4*)&T[cr * 36 + c0];
    }
}

// ---------------------------------------------------------------------------
// Main: 256 WGs = F(64) x B/64(4), 512 threads = 8 waves.
// wave w == r, lane l == b-offset. E staged in LDS as [r][bi][cin] (2304/36/1).
// W per (f,r,cout) is wave-uniform -> SGPRs via s_load_dwordx16 (pipelined).
// Output staged via LDS for coalesced float4 stores.
// ---------------------------------------------------------------------------

#define LOADW(WA, WB, OFS) \
    asm volatile("s_load_dwordx16 %0, %2, " OFS "\n\t" \
                 "s_load_dwordx16 %1, %2, " OFS "+64" \
                 : "=&s"(WA), "=&s"(WB) : "s"(wbase))

#define WAITW(WA, WB) \
    asm volatile("s_waitcnt lgkmcnt(0)" : "+s"(WA), "+s"(WB))

#define FMA16(WA, WB, C) do { \
    float s0 = E4[0].x * WA[0], s1 = E4[0].y * WA[1]; \
    float s2 = E4[0].z * WA[2], s3 = E4[0].w * WA[3]; \
    s0 = fmaf(E4[1].x, WA[4],  s0);  s1 = fmaf(E4[1].y, WA[5],  s1); \
    s2 = fmaf(E4[1].z, WA[6],  s2);  s3 = fmaf(E4[1].w, WA[7],  s3); \
    s0 = fmaf(E4[2].x, WA[8],  s0);  s1 = fmaf(E4[2].y, WA[9],  s1); \
    s2 = fmaf(E4[2].z, WA[10], s2);  s3 = fmaf(E4[2].w, WA[11], s3); \
    s0 = fmaf(E4[3].x, WA[12], s0);  s1 = fmaf(E4[3].y, WA[13], s1); \
    s2 = fmaf(E4[3].z, WA[14], s2);  s3 = fmaf(E4[3].w, WA[15], s3); \
    s0 = fmaf(E4[4].x, WB[0],  s0);  s1 = fmaf(E4[4].y, WB[1],  s1); \
    s2 = fmaf(E4[4].z, WB[2],  s2);  s3 = fmaf(E4[4].w, WB[3],  s3); \
    s0 = fmaf(E4[5].x, WB[4],  s0);  s1 = fmaf(E4[5].y, WB[5],  s1); \
    s2 = fmaf(E4[5].z, WB[6],  s2);  s3 = fmaf(E4[5].w, WB[7],  s3); \
    s0 = fmaf(E4[6].x, WB[8],  s0);  s1 = fmaf(E4[6].y, WB[9],  s1); \
    s2 = fmaf(E4[6].z, WB[10], s2);  s3 = fmaf(E4[6].w, WB[11], s3); \
    s0 = fmaf(E4[7].x, WB[12], s0);  s1 = fmaf(E4[7].y, WB[13], s1); \
    s2 = fmaf(E4[7].z, WB[14], s2);  s3 = fmaf(E4[7].w, WB[15], s3); \
    acc[C] = (s0 + s1) + (s2 + s3); \
} while (0)

__global__ __launch_bounds__(512) void lse_main(const float* __restrict__ ll,
                                                const float* __restrict__ wt,
                                                float* __restrict__ out) {
    __shared__ float S[18432];                 // 72 KB: E[r][bi][cin] then reused for out tile
    const int t  = threadIdx.x;
    const int w  = t >> 6;                     // wave id == r
    const int l  = t & 63;                     // lane
    const int f  = blockIdx.x >> 2;
    const int b0 = (blockIdx.x & 3) << 6;

    // ---- Phase 1: stage exp2(ll*log2e) -> S[r*2304 + bi*36 + cin] ----
    {
        const int cin = l >> 1;
        const int r0  = (l & 1) << 2;
        #pragma unroll
        for (int j = 0; j < 8; ++j) {
            const int bi = j * 8 + w;          // wave-uniform row
            const float4 v = *(const float4*)(ll + (((size_t)(b0 + bi) * F_ + f) << 8) + l * 4);
            S[(r0 + 0) * 2304 + bi * 36 + cin] = exp2f(v.x * LOG2E);
            S[(r0 + 1) * 2304 + bi * 36 + cin] = exp2f(v.y * LOG2E);
            S[(r0 + 2) * 2304 + bi * 36 + cin] = exp2f(v.z * LOG2E);
            S[(r0 + 3) * 2304 + bi * 36 + cin] = exp2f(v.w * LOG2E);
        }
    }
    __syncthreads();

    // ---- Phase 2: E -> registers, W -> SGPRs, 512 FMAs ----
    float4 E4[8];
    #pragma unroll
    for (int q = 0; q < 8; ++q)
        E4[q] = *(const float4*)&S[w * 2304 + l * 36 + q * 4];

    const float* wq = wt + ((size_t)f << 12) + (w << 5);   // wave-uniform
    const uint32_t wlo = __builtin_amdgcn_readfirstlane((uint32_t)(uintptr_t)wq);
    const uint32_t whi = __builtin_amdgcn_readfirstlane((uint32_t)((uintptr_t)wq >> 32));
    const uint64_t wbase = ((uint64_t)whi << 32) | wlo;

    float acc[16];
    f32x16 A0, B0, A1, B1;

    LOADW(A0, B0, "0");     WAITW(A0, B0);
    LOADW(A1, B1, "1024");  FMA16(A0, B0, 0);   WAITW(A1, B1);
    LOADW(A0, B0, "2048");  FMA16(A1, B1, 1);   WAITW(A0, B0);
    LOADW(A1, B1, "3072");  FMA16(A0, B0, 2);   WAITW(A1, B1);
    LOADW(A0, B0, "4096");  FMA16(A1, B1, 3);   WAITW(A0, B0);
    LOADW(A1, B1, "5120");  FMA16(A0, B0, 4);   WAITW(A1, B1);
    LOADW(A0, B0, "6144");  FMA16(A1, B1, 5);   WAITW(A0, B0);
    LOADW(A1, B1, "7168");  FMA16(A0, B0, 6);   WAITW(A1, B1);
    LOADW(A0, B0, "8192");  FMA16(A1, B1, 7);   WAITW(A0, B0);
    LOADW(A1, B1, "9216");  FMA16(A0, B0, 8);   WAITW(A1, B1);
    LOADW(A0, B0, "10240"); FMA16(A1, B1, 9);   WAITW(A0, B0);
    LOADW(A1, B1, "11264"); FMA16(A0, B0, 10);  WAITW(A1, B1);
    LOADW(A0, B0, "12288"); FMA16(A1, B1, 11);  WAITW(A0, B0);
    LOADW(A1, B1, "13312"); FMA16(A0, B0, 12);  WAITW(A1, B1);
    LOADW(A0, B0, "14336"); FMA16(A1, B1, 13);  WAITW(A0, B0);
    LOADW(A1, B1, "15360"); FMA16(A0, B0, 14);  WAITW(A1, B1);
    FMA16(A1, B1, 15);

    // ---- Phase 3: log, stage to LDS (reuse S), coalesced writeback ----
    __syncthreads();                           // all E reads done before overwrite
    #pragma unroll
    for (int c = 0; c < 16; ++c)
        S[l * 132 + c * 8 + w] = LN2 * log2f(acc[c]);
    __syncthreads();

    #pragma unroll
    for (int i = 0; i < 4; ++i) {
        const int q  = i * 512 + t;            // float4 idx in [64][128] tile
        const int bi = q >> 5, c0 = (q & 31) << 2;
        const float4 v = *(const float4*)&S[bi * 132 + c0];
        *(float4*)(out + ((size_t)(b0 + bi) << 13) + (f << 7) + c0) = v;
    }
}

extern "C" void kernel_launch(void* const* d_in, const int* in_sizes, int n_in,
                              void* d_out, int out_size, void* d_ws, size_t ws_size,
                              hipStream_t stream) {
    const float* ll     = (const float*)d_in[0];   // (B,F,CIN,R) f32
    const float* logits = (const float*)d_in[1];   // (F,CIN,COUT,R) f32
    float* out = (float*)d_out;                    // (B,F,COUT,R) f32
    float* wt  = (float*)d_ws;                     // 1 MB: softmax weights, transposed

    prep_softmax<<<dim3(F_), dim3(256), 0, stream>>>(logits, wt);
    lse_main<<<dim3((B_ / 64) * F_), dim3(512), 0, stream>>>(ll, wt, out);
}

// Round 4
// 16.033 us; speedup vs baseline: 1.1344x; 1.1344x over previous
//
#include <hip/hip_runtime.h>
#include <cstdint>

// out[b,f,cout,r] = log( sum_cin exp(ll[b,f,cin,r]) * softmax_cin(logits)[f,cin,cout,r] )
// B=256, F=64, CIN=32, COUT=16, R=8
#define LOG2E 1.4426950408889634f
#define LN2   0.6931471805599453f

// Single fused kernel. Grid = F(64) x (B/32)(8) = 512 WGs, 512 threads (8 waves).
// Wave w = r. Lane l: ch = l>>5 (cout half), b = l&31 (local batch).
// LDS (floats):
//   Tb [0..4224)     logits staging [32cin][128cr]; reused as out tile [32b][132]
//   Wb [4224..8320)  softmax weights [r][ch][cin][8cout]   (4096)
//   Eb [8320..17536) exp(ll) [r][32b][stride36]            (9216)
// 70.1 KB -> 2 WGs/CU, 16 waves/CU.
__global__ __launch_bounds__(512) void fused_lse(const float* __restrict__ ll,
                                                 const float* __restrict__ logits,
                                                 float* __restrict__ out) {
    __shared__ float S[17536];
    float* Tb = S;
    float* Wb = S + 4224;
    float* Eb = S + 8320;

    const int t  = threadIdx.x;
    const int w  = t >> 6;                 // wave id == r
    const int l  = t & 63;
    const int ch = l >> 5;                 // cout half (0..1)
    const int b  = l & 31;                 // local b (0..31)
    const int f  = (int)blockIdx.x >> 3;
    const int b0 = ((int)blockIdx.x & 7) << 5;

    // ---- Phase A: stage logits -> Tb (coalesced) and exp(ll) -> Eb (transposed) ----
    {
        const float* lg = logits + ((size_t)f << 12);
        *(float4*)&Tb[t * 8]     = *(const float4*)&lg[t * 8];
        *(float4*)&Tb[t * 8 + 4] = *(const float4*)&lg[t * 8 + 4];

        const int cin = l >> 1;
        const int r0  = (l & 1) << 2;
        #pragma unroll
        for (int j = 0; j < 4; ++j) {
            const int row = j * 8 + w;     // wave-uniform local b row
            const float4 v = *(const float4*)(ll + (((size_t)(b0 + row) * 64 + f) << 8) + l * 4);
            Eb[(r0 + 0) * 1152 + row * 36 + cin] = __builtin_amdgcn_exp2f(v.x * LOG2E);
            Eb[(r0 + 1) * 1152 + row * 36 + cin] = __builtin_amdgcn_exp2f(v.y * LOG2E);
            Eb[(r0 + 2) * 1152 + row * 36 + cin] = __builtin_amdgcn_exp2f(v.z * LOG2E);
            Eb[(r0 + 3) * 1152 + row * 36 + cin] = __builtin_amdgcn_exp2f(v.w * LOG2E);
        }
    }
    __syncthreads();

    // ---- Phase B: softmax over cin for each of 128 (cout,r) columns (threads 0..127) ----
    if (t < 128) {
        const int r_  = t & 7;
        const int co_ = t >> 3;            // cout 0..15
        float x[32];
        #pragma unroll
        for (int c = 0; c < 32; ++c) x[c] = Tb[c * 128 + t];
        float m = x[0];
        #pragma unroll
        for (int c = 1; c < 32; ++c) m = fmaxf(m, x[c]);
        float s = 0.f;
        #pragma unroll
        for (int c = 0; c < 32; ++c) { x[c] = __builtin_amdgcn_exp2f((x[c] - m) * LOG2E); s += x[c]; }
        const float inv = 1.0f / s;
        float* wrow = Wb + r_ * 512 + (co_ >> 3) * 256 + (co_ & 7);
        #pragma unroll
        for (int c = 0; c < 32; ++c) wrow[c * 8] = x[c] * inv;
    }
    __syncthreads();

    // ---- Phase C: acc[cout8] = sum_cin E[b][cin] * W[cin][cout8] ----
    float acc[8] = {0.f, 0.f, 0.f, 0.f, 0.f, 0.f, 0.f, 0.f};
    const float* Ew = Eb + w * 1152 + b * 36;            // per-lane E row
    const float* Ww = Wb + (w * 2 + ch) * 256;           // half-wave-uniform W slice
    #pragma unroll
    for (int cc = 0; cc < 8; ++cc) {
        const float4 e = *(const float4*)&Ew[cc * 4];
        #pragma unroll
        for (int i = 0; i < 4; ++i) {
            const float  ev = (i == 0) ? e.x : (i == 1) ? e.y : (i == 2) ? e.z : e.w;
            const float4 wa = *(const float4*)&Ww[(cc * 4 + i) * 8];
            const float4 wc = *(const float4*)&Ww[(cc * 4 + i) * 8 + 4];
            acc[0] = fmaf(ev, wa.x, acc[0]);
            acc[1] = fmaf(ev, wa.y, acc[1]);
            acc[2] = fmaf(ev, wa.z, acc[2]);
            acc[3] = fmaf(ev, wa.w, acc[3]);
            acc[4] = fmaf(ev, wc.x, acc[4]);
            acc[5] = fmaf(ev, wc.y, acc[5]);
            acc[6] = fmaf(ev, wc.z, acc[6]);
            acc[7] = fmaf(ev, wc.w, acc[7]);
        }
    }

    // ---- Phase D: log -> Tb (reuse; Tb reads all precede barrier 2) ----
    #pragma unroll
    for (int k = 0; k < 8; ++k)
        Tb[b * 132 + ((ch * 8 + k) << 3) + w] = LN2 * __builtin_amdgcn_logf(acc[k]);
    __syncthreads();

    // ---- Phase E: coalesced writeback of [32b][128cr] tile ----
    #pragma unroll
    for (int i = 0; i < 2; ++i) {
        const int q  = i * 512 + t;
        const int bi = q >> 5, c0 = (q & 31) << 2;
        *(float4*)(out + (size_t)(b0 + bi) * 8192 + (f << 7) + c0) =
            *(const float4*)&Tb[bi * 132 + c0];
    }
}

extern "C" void kernel_launch(void* const* d_in, const int* in_sizes, int n_in,
                              void* d_out, int out_size, void* d_ws, size_t ws_size,
                              hipStream_t stream) {
    const float* ll     = (const float*)d_in[0];   // (256,64,32,8) f32
    const float* logits = (const float*)d_in[1];   // (64,32,16,8) f32
    float* out = (float*)d_out;                    // (256,64,16,8) f32

    fused_lse<<<dim3(512), dim3(512), 0, stream>>>(ll, logits, out);
}